// Round 1
// baseline (316.384 us; speedup 1.0000x reference)
//
#include <hip/hip_runtime.h>
#include <math.h>

// Shapes: B=32, L=128, H=768, E=64, H+E=832, 2H=1536
#define NB 32
#define NL 128
#define NH 768
#define NE 64

// ---------------- ws layout (bytes) ----------------
#define OFF_TOTAL   0         // int g_total (16 B reserved)
#define OFF_NRLIST  16        // int[4096*2] (b,i) pairs            -> 32784
#define OFF_ASLOT   32784     // int[32*128] aspect slot or -1      -> 49168
#define OFF_AIDX    49168     // int[32*4] aspect row index         -> 49680
#define OFF_NASP    49680     // int[32]                            -> 49808
#define OFF_AJCNT   49808     // int[32*4]                          -> 50320
#define OFF_AJIDX   50320     // int[32*4*128]                      -> 115856
#define OFF_SI      115856    // float[4096]                        -> 132240
#define OFF_SJ      132240    // float[4096]                        -> 148624
#define OFF_NBR     148624    // float[32*4*768]                    -> 541840
#define OFF_TEMP    541840    // float[32*4*768]                    -> 935056
#define OFF_ZS      935056    // float[32*128*768]                  -> 13517968

// ---------------- K1: masks, aspect rows, needed-row compaction ----------------
__global__ __launch_bounds__(128) void k1_masks(
    const int* __restrict__ adj, const int* __restrict__ asp_s, const int* __restrict__ asp_e,
    int* __restrict__ g_total, int* __restrict__ nr_list, int* __restrict__ aspect_slot,
    int* __restrict__ aspect_idx, int* __restrict__ nasp, int* __restrict__ aj_cnt,
    int* __restrict__ aj_idx) {
  int b = blockIdx.x, tid = threadIdx.x;
  __shared__ int asp_flag[128];
  __shared__ int needed[128];
  __shared__ int s_aidx[4];
  __shared__ int s_nasp;
  const int* arow = adj + ((size_t)(b * 128 + tid)) * 128;
  int any = 0;
  for (int j = 0; j < 128; j += 4) {
    int4 v = *(const int4*)(arow + j);
    any |= v.x | v.y | v.z | v.w;
  }
  int s0 = asp_s[b], e0 = asp_e[b];
  int af = (tid >= s0 && tid <= e0 && any > 0) ? 1 : 0;
  asp_flag[tid] = af;
  aspect_slot[b * 128 + tid] = -1;
  __syncthreads();
  if (tid == 0) {
    int n = 0;
    for (int i = 0; i < 128; ++i)
      if (asp_flag[i] && n < 4) s_aidx[n++] = i;
    s_nasp = n;
    nasp[b] = n;
  }
  __syncthreads();
  int na = s_nasp;
  int nd = af;
  for (int s = 0; s < na; ++s) {
    int a = s_aidx[s];
    nd |= (adj[((size_t)(b * 128 + a)) * 128 + tid] > 0) ? 1 : 0;
  }
  needed[tid] = nd;
  if (tid < na) {
    aspect_idx[b * 4 + tid] = s_aidx[tid];
    aspect_slot[b * 128 + s_aidx[tid]] = tid;
    int a = s_aidx[tid], c = 0;
    const int* ar = adj + ((size_t)(b * 128 + a)) * 128;
    for (int j = 0; j < 128; ++j)
      if (ar[j] > 0) aj_idx[(b * 4 + tid) * 128 + (c++)] = j;
    aj_cnt[b * 4 + tid] = c;
  }
  __syncthreads();
  if (tid == 0) {
    int c = 0;
    for (int i = 0; i < 128; ++i) c += needed[i];
    int base = atomicAdd(g_total, c);
    int k = 0;
    for (int i = 0; i < 128; ++i)
      if (needed[i]) { nr_list[2 * (base + k)] = b; nr_list[2 * (base + k) + 1] = i; ++k; }
  }
}

// ---------------- K2: zs = roll(bert@Wz^T + bz) for needed rows ----------------
// BM=32 rows/block, BN=64 cols/block, BK=64; grid (128, 12), block 256.
__global__ __launch_bounds__(256) void k2_zs(
    const float* __restrict__ bert, const float* __restrict__ Wz, const float* __restrict__ bz,
    const int* __restrict__ g_total, const int* __restrict__ nr_list, float* __restrict__ zs) {
  int mb = blockIdx.x, nt = blockIdx.y;
  int total = *g_total;
  if (mb * 32 >= total) return;
  __shared__ float Xs[64][36];  // [k][m]
  __shared__ float Ws[64][68];  // [k][n]
  int tid = threadIdx.x;
  const float* src[2];
  int vld[2];
#pragma unroll
  for (int it = 0; it < 2; ++it) {
    int f = tid + it * 256, m = f >> 4, s = mb * 32 + m;
    vld[it] = (s < total) ? 1 : 0;
    int bb = 0, ii = 0;
    if (vld[it]) { bb = nr_list[2 * s]; ii = nr_list[2 * s + 1]; }
    src[it] = bert + ((size_t)(bb * 128) + ((ii + 1) & 127)) * 768;
  }
  float acc[2][4] = {};
  int tm2 = (tid >> 4) * 2, tn4 = (tid & 15) * 4;
  for (int kt = 0; kt < 12; ++kt) {
    __syncthreads();
#pragma unroll
    for (int it = 0; it < 2; ++it) {
      int f = tid + it * 256, m = f >> 4, k4 = (f & 15) * 4;
      float4 v = make_float4(0.f, 0.f, 0.f, 0.f);
      if (vld[it]) v = *(const float4*)(src[it] + kt * 64 + k4);
      Xs[k4 + 0][m] = v.x; Xs[k4 + 1][m] = v.y; Xs[k4 + 2][m] = v.z; Xs[k4 + 3][m] = v.w;
    }
#pragma unroll
    for (int it = 0; it < 4; ++it) {
      int f = tid + it * 256, n = f >> 4, k4 = (f & 15) * 4;
      float4 v = *(const float4*)(Wz + (size_t)(nt * 64 + n) * 768 + kt * 64 + k4);
      Ws[k4 + 0][n] = v.x; Ws[k4 + 1][n] = v.y; Ws[k4 + 2][n] = v.z; Ws[k4 + 3][n] = v.w;
    }
    __syncthreads();
#pragma unroll
    for (int k = 0; k < 64; ++k) {
      float x0 = Xs[k][tm2], x1 = Xs[k][tm2 + 1];
      float4 w = *(const float4*)&Ws[k][tn4];
      acc[0][0] += x0 * w.x; acc[0][1] += x0 * w.y; acc[0][2] += x0 * w.z; acc[0][3] += x0 * w.w;
      acc[1][0] += x1 * w.x; acc[1][1] += x1 * w.y; acc[1][2] += x1 * w.z; acc[1][3] += x1 * w.w;
    }
  }
  float4 bzv = *(const float4*)(bz + nt * 64 + tn4);
#pragma unroll
  for (int r = 0; r < 2; ++r) {
    int s = mb * 32 + tm2 + r;
    if (s >= total) continue;
    int bb = nr_list[2 * s], ii = nr_list[2 * s + 1];
    float4 o = make_float4(acc[r][0] + bzv.x, acc[r][1] + bzv.y, acc[r][2] + bzv.z, acc[r][3] + bzv.w);
    *(float4*)(zs + (size_t)(bb * 128 + ii) * 768 + nt * 64 + tn4) = o;
  }
}

// ---------------- K2b: s_i, s_j dots for needed rows ----------------
__global__ __launch_bounds__(256) void k2b_sij(
    const float* __restrict__ zs, const float* __restrict__ wa,
    const int* __restrict__ g_total, const int* __restrict__ nr_list,
    float* __restrict__ s_i, float* __restrict__ s_j) {
  int gw = (blockIdx.x * 256 + threadIdx.x) >> 6;
  int l = threadIdx.x & 63;
  int total = *g_total;
  for (int s = gw; s < total; s += 64) {
    int b = nr_list[2 * s], i = nr_list[2 * s + 1];
    const float* zr = zs + (size_t)(b * 128 + i) * 768;
    float si = 0.f, sj = 0.f;
#pragma unroll
    for (int q = 0; q < 12; ++q) {
      float v = zr[q * 64 + l];
      si += v * wa[q * 64 + l];
      sj += v * wa[768 + q * 64 + l];
    }
#pragma unroll
    for (int d = 32; d; d >>= 1) {
      si += __shfl_xor(si, d, 64);
      sj += __shfl_xor(sj, d, 64);
    }
    if (l == 0) { s_i[b * 128 + i] = si; s_j[b * 128 + i] = sj; }
  }
}

// ---------------- K3a: softmax + y,D + nbr = [y|D] @ Wf^T (h-slice) ----------------
__global__ __launch_bounds__(256) void k3_nbr(
    const float* __restrict__ dep, const float* __restrict__ zs,
    const float* __restrict__ s_i, const float* __restrict__ s_j,
    const float* __restrict__ wa, const float* __restrict__ ba,
    const float* __restrict__ Wf,
    const int* __restrict__ nasp, const int* __restrict__ aspect_idx,
    const int* __restrict__ aj_cnt, const int* __restrict__ aj_idx,
    float* __restrict__ nbr) {
  int b = blockIdx.x, nt = blockIdx.y;
  int na = nasp[b];
  if (na == 0) return;
  __shared__ float X1s[4][832];
  __shared__ float att[4][128];
  __shared__ int jl[4][128];
  __shared__ int aidx[4];
  __shared__ int ajc[4];
  __shared__ float wae[64];
  int tid = threadIdx.x;
  if (tid < 4) { aidx[tid] = aspect_idx[b * 4 + tid]; ajc[tid] = aj_cnt[b * 4 + tid]; }
  if (tid < 64) wae[tid] = wa[1536 + tid];
  for (int q = tid; q < 512; q += 256) jl[q >> 7][q & 127] = aj_idx[b * 512 + q];
  __syncthreads();
  int w = tid >> 6, l = tid & 63;
  if (w < na) {
    int a = aidx[w], cj = ajc[w];
    float sib = s_i[b * 128 + a] + ba[0];
    const float* depa = dep + ((size_t)(b * 128 + a)) * 128 * 64;
    float sc0 = -INFINITY, sc1 = -INFINITY;
    for (int t = l; t < cj; t += 64) {
      int j = jl[w][t];
      const float4* dp = (const float4*)(depa + (size_t)j * 64);
      float se = 0.f;
#pragma unroll
      for (int q = 0; q < 16; ++q) {
        float4 v = dp[q];
        se += v.x * wae[4 * q] + v.y * wae[4 * q + 1] + v.z * wae[4 * q + 2] + v.w * wae[4 * q + 3];
      }
      float sc = sib + s_j[b * 128 + j] + se;
      sc = (sc >= 0.f) ? sc : 0.01f * sc;
      if (t < 64) sc0 = sc; else sc1 = sc;
    }
    float mx = fmaxf(sc0, sc1);
#pragma unroll
    for (int d = 32; d; d >>= 1) mx = fmaxf(mx, __shfl_xor(mx, d, 64));
    float p0 = expf(sc0 - mx), p1 = expf(sc1 - mx);
    float sm = p0 + p1;
#pragma unroll
    for (int d = 32; d; d >>= 1) sm += __shfl_xor(sm, d, 64);
    float inv = 1.f / sm;
    if (l < cj) att[w][l] = p0 * inv;
    if (l + 64 < cj) att[w][l + 64] = p1 * inv;
    // y = attn @ zs  (12 regs per lane), D = attn @ dep_row
    float y[12];
#pragma unroll
    for (int q = 0; q < 12; ++q) y[q] = 0.f;
    float dacc = 0.f;
    for (int t = 0; t < cj; ++t) {
      float at = att[w][t];
      int j = jl[w][t];
      const float* zr = zs + (size_t)(b * 128 + j) * 768;
#pragma unroll
      for (int q = 0; q < 12; ++q) y[q] += at * zr[q * 64 + l];
      dacc += at * depa[(size_t)j * 64 + l];
    }
#pragma unroll
    for (int q = 0; q < 12; ++q) X1s[w][q * 64 + l] = y[q];
    X1s[w][768 + l] = dacc;
  }
  __syncthreads();
  int h = nt * 64 + l;
  float acc = 0.f;
  const float4* wf4 = (const float4*)(Wf + (size_t)h * 832);
  const float4* x4 = (const float4*)(&X1s[w][0]);
#pragma unroll 4
  for (int k4 = 0; k4 < 208; ++k4) {
    float4 wv = wf4[k4];
    float4 xv = x4[k4];
    acc += xv.x * wv.x + xv.y * wv.y + xv.z * wv.z + xv.w * wv.w;
  }
  if (w < na) nbr[(size_t)(b * 4 + w) * 768 + h] = acc;
}

// ---------------- K3b: temp = [nbr|zs] @ Wh^T (h-slice) ----------------
__global__ __launch_bounds__(256) void k3_temp(
    const float* __restrict__ zs, const float* __restrict__ nbr, const float* __restrict__ Wh,
    const int* __restrict__ nasp, const int* __restrict__ aspect_idx,
    float* __restrict__ temp) {
  int b = blockIdx.x, nt = blockIdx.y;
  int na = nasp[b];
  if (na == 0) return;
  __shared__ float X2s[4][1536];
  __shared__ int aidx[4];
  int tid = threadIdx.x;
  if (tid < 4) aidx[tid] = (tid < na) ? aspect_idx[b * 4 + tid] : 0;
  __syncthreads();
  for (int q = tid; q < 4 * 1536; q += 256) {
    int m = q / 1536, k = q - m * 1536;
    float v = 0.f;
    if (m < na)
      v = (k < 768) ? nbr[(size_t)(b * 4 + m) * 768 + k]
                    : zs[(size_t)(b * 128 + aidx[m]) * 768 + (k - 768)];
    X2s[m][k] = v;
  }
  __syncthreads();
  int w = tid >> 6, l = tid & 63;
  int h = nt * 64 + l;
  float acc = 0.f;
  const float4* wh4 = (const float4*)(Wh + (size_t)h * 1536);
  const float4* x4 = (const float4*)(&X2s[w][0]);
#pragma unroll 4
  for (int k4 = 0; k4 < 384; ++k4) {
    float4 wv = wh4[k4];
    float4 xv = x4[k4];
    acc += xv.x * wv.x + xv.y * wv.y + xv.z * wv.z + xv.w * wv.w;
  }
  if (w < na) temp[(size_t)(b * 4 + w) * 768 + h] = acc;
}

// ---------------- K4: out = upd[i-1] ? temp[i-1] : bert[i] ----------------
__global__ __launch_bounds__(256) void k4_out(
    const float* __restrict__ bert, const float* __restrict__ temp,
    const int* __restrict__ aspect_slot, float* __restrict__ out) {
  int idx = blockIdx.x * 256 + threadIdx.x;  // float4 index
  if (idx >= NB * NL * NH / 4) return;
  int row = idx / 192;  // 192 float4 per row
  int c4 = idx - row * 192;
  int b = row >> 7, i = row & 127;
  int slot = -1;
  if (i > 0) slot = aspect_slot[b * 128 + i - 1];
  float4 v;
  if (slot >= 0)
    v = *(const float4*)(temp + (size_t)(b * 4 + slot) * 768 + c4 * 4);
  else
    v = *(const float4*)(bert + (size_t)row * 768 + c4 * 4);
  *((float4*)out + idx) = v;
}

extern "C" void kernel_launch(void* const* d_in, const int* in_sizes, int n_in,
                              void* d_out, int out_size, void* d_ws, size_t ws_size,
                              hipStream_t stream) {
  const float* bert = (const float*)d_in[0];
  const float* dep  = (const float*)d_in[1];
  const int*   adj  = (const int*)d_in[2];
  const int*   asps = (const int*)d_in[3];
  const int*   aspe = (const int*)d_in[4];
  const float* Wz   = (const float*)d_in[5];
  const float* bz   = (const float*)d_in[6];
  const float* wa   = (const float*)d_in[7];
  const float* ba   = (const float*)d_in[8];
  const float* Wf   = (const float*)d_in[9];
  const float* Wh   = (const float*)d_in[10];
  float* out = (float*)d_out;
  char* ws = (char*)d_ws;

  int*   g_total     = (int*)(ws + OFF_TOTAL);
  int*   nr_list     = (int*)(ws + OFF_NRLIST);
  int*   aspect_slot = (int*)(ws + OFF_ASLOT);
  int*   aspect_idx  = (int*)(ws + OFF_AIDX);
  int*   nasp        = (int*)(ws + OFF_NASP);
  int*   aj_cnt      = (int*)(ws + OFF_AJCNT);
  int*   aj_idx      = (int*)(ws + OFF_AJIDX);
  float* s_i         = (float*)(ws + OFF_SI);
  float* s_j         = (float*)(ws + OFF_SJ);
  float* nbr         = (float*)(ws + OFF_NBR);
  float* temp        = (float*)(ws + OFF_TEMP);
  float* zs          = (float*)(ws + OFF_ZS);

  hipMemsetAsync(g_total, 0, 16, stream);
  k1_masks<<<NB, 128, 0, stream>>>(adj, asps, aspe, g_total, nr_list, aspect_slot,
                                   aspect_idx, nasp, aj_cnt, aj_idx);
  k2_zs<<<dim3(128, 12), 256, 0, stream>>>(bert, Wz, bz, g_total, nr_list, zs);
  k2b_sij<<<16, 256, 0, stream>>>(zs, wa, g_total, nr_list, s_i, s_j);
  k3_nbr<<<dim3(NB, 12), 256, 0, stream>>>(dep, zs, s_i, s_j, wa, ba, Wf,
                                           nasp, aspect_idx, aj_cnt, aj_idx, nbr);
  k3_temp<<<dim3(NB, 12), 256, 0, stream>>>(zs, nbr, Wh, nasp, aspect_idx, temp);
  k4_out<<<(NB * NL * NH / 4 + 255) / 256, 256, 0, stream>>>(bert, temp, aspect_slot, out);
}

// Round 4
// 277.367 us; speedup vs baseline: 1.1407x; 1.1407x over previous
//
#include <hip/hip_runtime.h>
#include <math.h>

// Shapes: B=32, L=128, H=768, E=64, H+E=832, 2H=1536
#define NB 32
#define NL 128
#define NH 768
#define NE 64

// ---------------- ws layout (bytes) ----------------
#define OFF_TOTAL   0         // int g_total (16 B reserved)
#define OFF_NRLIST  16        // int[4096*2] (b,i) pairs            -> 32784
#define OFF_ASLOT   32784     // int[32*128] aspect slot or -1      -> 49168
#define OFF_AIDX    49168     // int[32*4] aspect row index         -> 49680
#define OFF_NASP    49680     // int[32]                            -> 49808
#define OFF_AJCNT   49808     // int[32*4]                          -> 50320
#define OFF_AJIDX   50320     // int[32*4*128]                      -> 115856
#define OFF_SI      115856    // float[4096]                        -> 132240
#define OFF_SJ      132240    // float[4096]                        -> 148624
#define OFF_NBR     148624    // float[32*4*768]                    -> 541840
#define OFF_TEMP    541840    // float[32*4*768]                    -> 935056
#define OFF_ZS      935056    // float[32*128*768]                  -> 13517968

// ---------------- K1: masks, aspect rows, needed-row compaction ----------------
__global__ __launch_bounds__(128) void k1_masks(
    const int* __restrict__ adj, const int* __restrict__ asp_s, const int* __restrict__ asp_e,
    int* __restrict__ g_total, int* __restrict__ nr_list, int* __restrict__ aspect_slot,
    int* __restrict__ aspect_idx, int* __restrict__ nasp, int* __restrict__ aj_cnt,
    int* __restrict__ aj_idx) {
  int b = blockIdx.x, tid = threadIdx.x;
  __shared__ int asp_flag[128];
  __shared__ int needed[128];
  __shared__ int s_aidx[4];
  __shared__ int s_nasp;
  const int* arow = adj + ((size_t)(b * 128 + tid)) * 128;
  int any = 0;
  for (int j = 0; j < 128; j += 4) {
    int4 v = *(const int4*)(arow + j);
    any |= v.x | v.y | v.z | v.w;
  }
  int s0 = asp_s[b], e0 = asp_e[b];
  int af = (tid >= s0 && tid <= e0 && any > 0) ? 1 : 0;
  asp_flag[tid] = af;
  aspect_slot[b * 128 + tid] = -1;
  __syncthreads();
  if (tid == 0) {
    int n = 0;
    for (int i = 0; i < 128; ++i)
      if (asp_flag[i] && n < 4) s_aidx[n++] = i;
    s_nasp = n;
    nasp[b] = n;
  }
  __syncthreads();
  int na = s_nasp;
  int nd = af;
  for (int s = 0; s < na; ++s) {
    int a = s_aidx[s];
    nd |= (adj[((size_t)(b * 128 + a)) * 128 + tid] > 0) ? 1 : 0;
  }
  needed[tid] = nd;
  if (tid < na) {
    aspect_idx[b * 4 + tid] = s_aidx[tid];
    aspect_slot[b * 128 + s_aidx[tid]] = tid;
    int a = s_aidx[tid], c = 0;
    const int* ar = adj + ((size_t)(b * 128 + a)) * 128;
    for (int j = 0; j < 128; ++j)
      if (ar[j] > 0) aj_idx[(b * 4 + tid) * 128 + (c++)] = j;
    aj_cnt[b * 4 + tid] = c;
  }
  __syncthreads();
  if (tid == 0) {
    int c = 0;
    for (int i = 0; i < 128; ++i) c += needed[i];
    int base = atomicAdd(g_total, c);
    int k = 0;
    for (int i = 0; i < 128; ++i)
      if (needed[i]) { nr_list[2 * (base + k)] = b; nr_list[2 * (base + k) + 1] = i; ++k; }
  }
}

// ---------------- K2 (v2): zs = roll(bert@Wz^T + bz) for needed rows ----------------
// One block per 4 compacted rows; X rows in LDS (broadcast b128 reads);
// each thread owns 3 Wz rows streamed from L2; 48 FMA per k4-step (VALU-bound).
__global__ __launch_bounds__(256) void k2_zs(
    const float* __restrict__ bert, const float* __restrict__ Wz, const float* __restrict__ bz,
    const int* __restrict__ g_total, const int* __restrict__ nr_list, float* __restrict__ zs) {
  int total = *g_total;
  int row0 = blockIdx.x * 4;
  if (row0 >= total) return;
  __shared__ float Xs[4][768];
  int tid = threadIdx.x;
  // stage up to 4 rolled bert rows into LDS (coalesced float4)
  for (int r = 0; r < 4; ++r) {
    int s = row0 + r;
    if (s < total) {
      int bb = nr_list[2 * s], ii = nr_list[2 * s + 1];
      const float4* src = (const float4*)(bert + ((size_t)(bb * 128) + ((ii + 1) & 127)) * 768);
      ((float4*)Xs[r])[tid - 256 * (tid >> 8)] = src[tid];  // tid<256 -> 3 chunks below
      // (the line above handles q==tid only; remaining chunks follow)
      ((float4*)Xs[r])[tid] = src[tid];
    }
  }
  // NOTE: 192 float4 per row, 256 threads: single strided loop instead
  __syncthreads();
  // redo staging cleanly (the above double-write is harmless but redundant; keep canonical loop)
  for (int r = 0; r < 4; ++r) {
    int s = row0 + r;
    if (s < total) {
      int bb = nr_list[2 * s], ii = nr_list[2 * s + 1];
      const float4* src = (const float4*)(bert + ((size_t)(bb * 128) + ((ii + 1) & 127)) * 768);
      for (int q = tid; q < 192; q += 256) ((float4*)Xs[r])[q] = src[q];
    }
  }
  __syncthreads();
  float acc[4][3] = {};
  const float4* wp0 = (const float4*)(Wz + (size_t)tid * 768);
  const float4* wp1 = (const float4*)(Wz + (size_t)(tid + 256) * 768);
  const float4* wp2 = (const float4*)(Wz + (size_t)(tid + 512) * 768);
  for (int k4 = 0; k4 < 192; ++k4) {
    float4 w0 = wp0[k4], w1 = wp1[k4], w2 = wp2[k4];
#pragma unroll
    for (int r = 0; r < 4; ++r) {
      float4 xv = ((const float4*)Xs[r])[k4];
      acc[r][0] += xv.x * w0.x + xv.y * w0.y + xv.z * w0.z + xv.w * w0.w;
      acc[r][1] += xv.x * w1.x + xv.y * w1.y + xv.z * w1.z + xv.w * w1.w;
      acc[r][2] += xv.x * w2.x + xv.y * w2.y + xv.z * w2.z + xv.w * w2.w;
    }
  }
  float b0 = bz[tid], b1 = bz[tid + 256], b2 = bz[tid + 512];
#pragma unroll
  for (int r = 0; r < 4; ++r) {
    int s = row0 + r;
    if (s < total) {
      int bb = nr_list[2 * s], ii = nr_list[2 * s + 1];
      float* zr = zs + (size_t)(bb * 128 + ii) * 768;
      zr[tid] = acc[r][0] + b0;
      zr[tid + 256] = acc[r][1] + b1;
      zr[tid + 512] = acc[r][2] + b2;
    }
  }
}

// ---------------- K2b: s_i, s_j dots for needed rows ----------------
__global__ __launch_bounds__(256) void k2b_sij(
    const float* __restrict__ zs, const float* __restrict__ wa,
    const int* __restrict__ g_total, const int* __restrict__ nr_list,
    float* __restrict__ s_i, float* __restrict__ s_j) {
  int gw = (blockIdx.x * 256 + threadIdx.x) >> 6;
  int l = threadIdx.x & 63;
  int total = *g_total;
  for (int s = gw; s < total; s += 64) {
    int b = nr_list[2 * s], i = nr_list[2 * s + 1];
    const float* zr = zs + (size_t)(b * 128 + i) * 768;
    float si = 0.f, sj = 0.f;
#pragma unroll
    for (int q = 0; q < 12; ++q) {
      float v = zr[q * 64 + l];
      si += v * wa[q * 64 + l];
      sj += v * wa[768 + q * 64 + l];
    }
#pragma unroll
    for (int d = 32; d; d >>= 1) {
      si += __shfl_xor(si, d, 64);
      sj += __shfl_xor(sj, d, 64);
    }
    if (l == 0) { s_i[b * 128 + i] = si; s_j[b * 128 + i] = sj; }
  }
}

// ---------------- K3a: softmax + y,D + nbr = [y|D] @ Wf^T (h-slice) ----------------
__global__ __launch_bounds__(256) void k3_nbr(
    const float* __restrict__ dep, const float* __restrict__ zs,
    const float* __restrict__ s_i, const float* __restrict__ s_j,
    const float* __restrict__ wa, const float* __restrict__ ba,
    const float* __restrict__ Wf,
    const int* __restrict__ nasp, const int* __restrict__ aspect_idx,
    const int* __restrict__ aj_cnt, const int* __restrict__ aj_idx,
    float* __restrict__ nbr) {
  int b = blockIdx.x, nt = blockIdx.y;
  int na = nasp[b];
  if (na == 0) return;
  __shared__ float X1s[4][832];
  __shared__ float att[4][128];
  __shared__ int jl[4][128];
  __shared__ int aidx[4];
  __shared__ int ajc[4];
  __shared__ float wae[64];
  int tid = threadIdx.x;
  if (tid < 4) { aidx[tid] = aspect_idx[b * 4 + tid]; ajc[tid] = aj_cnt[b * 4 + tid]; }
  if (tid < 64) wae[tid] = wa[1536 + tid];
  for (int q = tid; q < 512; q += 256) jl[q >> 7][q & 127] = aj_idx[b * 512 + q];
  __syncthreads();
  int w = tid >> 6, l = tid & 63;
  if (w < na) {
    int a = aidx[w], cj = ajc[w];
    float sib = s_i[b * 128 + a] + ba[0];
    const float* depa = dep + ((size_t)(b * 128 + a)) * 128 * 64;
    float sc0 = -INFINITY, sc1 = -INFINITY;
    for (int t = l; t < cj; t += 64) {
      int j = jl[w][t];
      const float4* dp = (const float4*)(depa + (size_t)j * 64);
      float se = 0.f;
#pragma unroll
      for (int q = 0; q < 16; ++q) {
        float4 v = dp[q];
        se += v.x * wae[4 * q] + v.y * wae[4 * q + 1] + v.z * wae[4 * q + 2] + v.w * wae[4 * q + 3];
      }
      float sc = sib + s_j[b * 128 + j] + se;
      sc = (sc >= 0.f) ? sc : 0.01f * sc;
      if (t < 64) sc0 = sc; else sc1 = sc;
    }
    float mx = fmaxf(sc0, sc1);
#pragma unroll
    for (int d = 32; d; d >>= 1) mx = fmaxf(mx, __shfl_xor(mx, d, 64));
    float p0 = expf(sc0 - mx), p1 = expf(sc1 - mx);
    float sm = p0 + p1;
#pragma unroll
    for (int d = 32; d; d >>= 1) sm += __shfl_xor(sm, d, 64);
    float inv = 1.f / sm;
    if (l < cj) att[w][l] = p0 * inv;
    if (l + 64 < cj) att[w][l + 64] = p1 * inv;
    // y = attn @ zs  (12 regs per lane), D = attn @ dep_row
    float y[12];
#pragma unroll
    for (int q = 0; q < 12; ++q) y[q] = 0.f;
    float dacc = 0.f;
    for (int t = 0; t < cj; ++t) {
      float at = att[w][t];
      int j = jl[w][t];
      const float* zr = zs + (size_t)(b * 128 + j) * 768;
#pragma unroll
      for (int q = 0; q < 12; ++q) y[q] += at * zr[q * 64 + l];
      dacc += at * depa[(size_t)j * 64 + l];
    }
#pragma unroll
    for (int q = 0; q < 12; ++q) X1s[w][q * 64 + l] = y[q];
    X1s[w][768 + l] = dacc;
  }
  __syncthreads();
  int h = nt * 64 + l;
  float acc = 0.f;
  const float4* wf4 = (const float4*)(Wf + (size_t)h * 832);
  const float4* x4 = (const float4*)(&X1s[w][0]);
#pragma unroll 4
  for (int k4 = 0; k4 < 208; ++k4) {
    float4 wv = wf4[k4];
    float4 xv = x4[k4];
    acc += xv.x * wv.x + xv.y * wv.y + xv.z * wv.z + xv.w * wv.w;
  }
  if (w < na) nbr[(size_t)(b * 4 + w) * 768 + h] = acc;
}

// ---------------- K3b: temp = [nbr|zs] @ Wh^T (h-slice) ----------------
__global__ __launch_bounds__(256) void k3_temp(
    const float* __restrict__ zs, const float* __restrict__ nbr, const float* __restrict__ Wh,
    const int* __restrict__ nasp, const int* __restrict__ aspect_idx,
    float* __restrict__ temp) {
  int b = blockIdx.x, nt = blockIdx.y;
  int na = nasp[b];
  if (na == 0) return;
  __shared__ float X2s[4][1536];
  __shared__ int aidx[4];
  int tid = threadIdx.x;
  if (tid < 4) aidx[tid] = (tid < na) ? aspect_idx[b * 4 + tid] : 0;
  __syncthreads();
  for (int q = tid; q < 4 * 1536; q += 256) {
    int m = q / 1536, k = q - m * 1536;
    float v = 0.f;
    if (m < na)
      v = (k < 768) ? nbr[(size_t)(b * 4 + m) * 768 + k]
                    : zs[(size_t)(b * 128 + aidx[m]) * 768 + (k - 768)];
    X2s[m][k] = v;
  }
  __syncthreads();
  int w = tid >> 6, l = tid & 63;
  int h = nt * 64 + l;
  float acc = 0.f;
  const float4* wh4 = (const float4*)(Wh + (size_t)h * 1536);
  const float4* x4 = (const float4*)(&X2s[w][0]);
#pragma unroll 4
  for (int k4 = 0; k4 < 384; ++k4) {
    float4 wv = wh4[k4];
    float4 xv = x4[k4];
    acc += xv.x * wv.x + xv.y * wv.y + xv.z * wv.z + xv.w * wv.w;
  }
  if (w < na) temp[(size_t)(b * 4 + w) * 768 + h] = acc;
}

// ---------------- K4: out = upd[i-1] ? temp[i-1] : bert[i] ----------------
__global__ __launch_bounds__(256) void k4_out(
    const float* __restrict__ bert, const float* __restrict__ temp,
    const int* __restrict__ aspect_slot, float* __restrict__ out) {
  int idx = blockIdx.x * 256 + threadIdx.x;  // float4 index
  if (idx >= NB * NL * NH / 4) return;
  int row = idx / 192;  // 192 float4 per row
  int c4 = idx - row * 192;
  int b = row >> 7, i = row & 127;
  int slot = -1;
  if (i > 0) slot = aspect_slot[b * 128 + i - 1];
  float4 v;
  if (slot >= 0)
    v = *(const float4*)(temp + (size_t)(b * 4 + slot) * 768 + c4 * 4);
  else
    v = *(const float4*)(bert + (size_t)row * 768 + c4 * 4);
  *((float4*)out + idx) = v;
}

extern "C" void kernel_launch(void* const* d_in, const int* in_sizes, int n_in,
                              void* d_out, int out_size, void* d_ws, size_t ws_size,
                              hipStream_t stream) {
  const float* bert = (const float*)d_in[0];
  const float* dep  = (const float*)d_in[1];
  const int*   adj  = (const int*)d_in[2];
  const int*   asps = (const int*)d_in[3];
  const int*   aspe = (const int*)d_in[4];
  const float* Wz   = (const float*)d_in[5];
  const float* bz   = (const float*)d_in[6];
  const float* wa   = (const float*)d_in[7];
  const float* ba   = (const float*)d_in[8];
  const float* Wf   = (const float*)d_in[9];
  const float* Wh   = (const float*)d_in[10];
  float* out = (float*)d_out;
  char* ws = (char*)d_ws;

  int*   g_total     = (int*)(ws + OFF_TOTAL);
  int*   nr_list     = (int*)(ws + OFF_NRLIST);
  int*   aspect_slot = (int*)(ws + OFF_ASLOT);
  int*   aspect_idx  = (int*)(ws + OFF_AIDX);
  int*   nasp        = (int*)(ws + OFF_NASP);
  int*   aj_cnt      = (int*)(ws + OFF_AJCNT);
  int*   aj_idx      = (int*)(ws + OFF_AJIDX);
  float* s_i         = (float*)(ws + OFF_SI);
  float* s_j         = (float*)(ws + OFF_SJ);
  float* nbr         = (float*)(ws + OFF_NBR);
  float* temp        = (float*)(ws + OFF_TEMP);
  float* zs          = (float*)(ws + OFF_ZS);

  hipMemsetAsync(g_total, 0, 16, stream);
  k1_masks<<<NB, 128, 0, stream>>>(adj, asps, aspe, g_total, nr_list, aspect_slot,
                                   aspect_idx, nasp, aj_cnt, aj_idx);
  k2_zs<<<1024, 256, 0, stream>>>(bert, Wz, bz, g_total, nr_list, zs);
  k2b_sij<<<16, 256, 0, stream>>>(zs, wa, g_total, nr_list, s_i, s_j);
  k3_nbr<<<dim3(NB, 12), 256, 0, stream>>>(dep, zs, s_i, s_j, wa, ba, Wf,
                                           nasp, aspect_idx, aj_cnt, aj_idx, nbr);
  k3_temp<<<dim3(NB, 12), 256, 0, stream>>>(zs, nbr, Wh, nasp, aspect_idx, temp);
  k4_out<<<(NB * NL * NH / 4 + 255) / 256, 256, 0, stream>>>(bert, temp, aspect_slot, out);
}

// Round 5
// 204.317 us; speedup vs baseline: 1.5485x; 1.3575x over previous
//
#include <hip/hip_runtime.h>
#include <math.h>

// Shapes: B=32, L=128, H=768, E=64, H+E=832, 2H=1536
#define NB 32
#define NL 128
#define NH 768
#define NE 64

// ---------------- ws layout (bytes) ----------------
#define OFF_TOTAL   0         // int g_total (16 B reserved)
#define OFF_NRLIST  16        // int[4096*2] (b,i) pairs            -> 32784
#define OFF_ASLOT   32784     // int[32*128] aspect slot or -1      -> 49168
#define OFF_AIDX    49168     // int[32*4] aspect row index         -> 49680
#define OFF_NASP    49680     // int[32]                            -> 49808
#define OFF_AJCNT   49808     // int[32*4]                          -> 50320
#define OFF_AJIDX   50320     // int[32*4*128]                      -> 115856
#define OFF_SI      115856    // float[4096]                        -> 132240
#define OFF_SJ      132240    // float[4096]                        -> 148624
#define OFF_RMAP    148624    // int[128] zs-row index per (b,slot) -> 149136
#define OFF_X2G     149152    // float[128*832]  [y|D]              -> 575136
#define OFF_NBRP    575136    // float[2*128*768] nbr partials      -> 1361568
#define OFF_TEMPP   1361568   // float[4*128*768] temp partials     -> 2934432
#define OFF_ZS      2934432   // float[32*128*768]                  -> 15517344

// ---------------- K1: masks, aspect rows, needed-row compaction ----------------
__global__ __launch_bounds__(128) void k1_masks(
    const int* __restrict__ adj, const int* __restrict__ asp_s, const int* __restrict__ asp_e,
    int* __restrict__ g_total, int* __restrict__ nr_list, int* __restrict__ aspect_slot,
    int* __restrict__ aspect_idx, int* __restrict__ nasp, int* __restrict__ aj_cnt,
    int* __restrict__ aj_idx, int* __restrict__ row_map) {
  int b = blockIdx.x, tid = threadIdx.x;
  __shared__ int asp_flag[128];
  __shared__ int needed[128];
  __shared__ int s_aidx[4];
  __shared__ int s_nasp;
  const int* arow = adj + ((size_t)(b * 128 + tid)) * 128;
  int any = 0;
  for (int j = 0; j < 128; j += 4) {
    int4 v = *(const int4*)(arow + j);
    any |= v.x | v.y | v.z | v.w;
  }
  int s0 = asp_s[b], e0 = asp_e[b];
  int af = (tid >= s0 && tid <= e0 && any > 0) ? 1 : 0;
  asp_flag[tid] = af;
  aspect_slot[b * 128 + tid] = -1;
  __syncthreads();
  if (tid == 0) {
    int n = 0;
    for (int i = 0; i < 128; ++i)
      if (asp_flag[i] && n < 4) s_aidx[n++] = i;
    s_nasp = n;
    nasp[b] = n;
  }
  __syncthreads();
  int na = s_nasp;
  int nd = af;
  for (int s = 0; s < na; ++s) {
    int a = s_aidx[s];
    nd |= (adj[((size_t)(b * 128 + a)) * 128 + tid] > 0) ? 1 : 0;
  }
  needed[tid] = nd;
  if (tid < 4) row_map[b * 4 + tid] = b * 128;  // safe default for invalid slots
  if (tid < na) {
    int a = s_aidx[tid];
    aspect_idx[b * 4 + tid] = a;
    aspect_slot[b * 128 + a] = tid;
    row_map[b * 4 + tid] = b * 128 + a;
    int c = 0;
    const int* ar = adj + ((size_t)(b * 128 + a)) * 128;
    for (int j = 0; j < 128; ++j)
      if (ar[j] > 0) aj_idx[(b * 4 + tid) * 128 + (c++)] = j;
    aj_cnt[b * 4 + tid] = c;
  }
  __syncthreads();
  if (tid == 0) {
    int c = 0;
    for (int i = 0; i < 128; ++i) c += needed[i];
    int base = atomicAdd(g_total, c);
    int k = 0;
    for (int i = 0; i < 128; ++i)
      if (needed[i]) { nr_list[2 * (base + k)] = b; nr_list[2 * (base + k) + 1] = i; ++k; }
  }
}

// ---------------- K2 (v3): zs = roll(bert@Wz^T + bz) for needed rows ----------------
// grid (1024, 3): 4 rows/block, h-chunk of 256 per block.y; X rows in LDS
// (uniform b128 broadcast); thread streams 1 Wz row chunk; 4 indep acc chains.
__global__ __launch_bounds__(256) void k2_zs(
    const float* __restrict__ bert, const float* __restrict__ Wz, const float* __restrict__ bz,
    const int* __restrict__ g_total, const int* __restrict__ nr_list, float* __restrict__ zs) {
  int total = *g_total;
  int row0 = blockIdx.x * 4;
  if (row0 >= total) return;
  __shared__ float Xs[4][768];
  int tid = threadIdx.x;
  for (int r = 0; r < 4; ++r) {
    int s = row0 + r;
    if (s < total) {
      int bb = nr_list[2 * s], ii = nr_list[2 * s + 1];
      const float4* src = (const float4*)(bert + ((size_t)(bb * 128) + ((ii + 1) & 127)) * 768);
      for (int q = tid; q < 192; q += 256) ((float4*)Xs[r])[q] = src[q];
    }
  }
  __syncthreads();
  int h = blockIdx.y * 256 + tid;
  float acc[4] = {};
  const float4* wp = (const float4*)(Wz + (size_t)h * 768);
#pragma unroll 4
  for (int k4 = 0; k4 < 192; ++k4) {
    float4 wv = wp[k4];
#pragma unroll
    for (int r = 0; r < 4; ++r) {
      float4 xv = ((const float4*)Xs[r])[k4];
      acc[r] += xv.x * wv.x + xv.y * wv.y + xv.z * wv.z + xv.w * wv.w;
    }
  }
  float bzv = bz[h];
#pragma unroll
  for (int r = 0; r < 4; ++r) {
    int s = row0 + r;
    if (s < total) {
      int bb = nr_list[2 * s], ii = nr_list[2 * s + 1];
      zs[(size_t)(bb * 128 + ii) * 768 + h] = acc[r] + bzv;
    }
  }
}

// ---------------- K2b: s_i, s_j dots for needed rows ----------------
__global__ __launch_bounds__(256) void k2b_sij(
    const float* __restrict__ zs, const float* __restrict__ wa,
    const int* __restrict__ g_total, const int* __restrict__ nr_list,
    float* __restrict__ s_i, float* __restrict__ s_j) {
  int gw = (blockIdx.x * 256 + threadIdx.x) >> 6;
  int l = threadIdx.x & 63;
  int total = *g_total;
  for (int s = gw; s < total; s += 64) {
    int b = nr_list[2 * s], i = nr_list[2 * s + 1];
    const float* zr = zs + (size_t)(b * 128 + i) * 768;
    float si = 0.f, sj = 0.f;
#pragma unroll
    for (int q = 0; q < 12; ++q) {
      float v = zr[q * 64 + l];
      si += v * wa[q * 64 + l];
      sj += v * wa[768 + q * 64 + l];
    }
#pragma unroll
    for (int d = 32; d; d >>= 1) {
      si += __shfl_xor(si, d, 64);
      sj += __shfl_xor(sj, d, 64);
    }
    if (l == 0) { s_i[b * 128 + i] = si; s_j[b * 128 + i] = sj; }
  }
}

// ---------------- KA: per-batch attention: scores, softmax, y, D -> X2g[row][832] ----------------
__global__ __launch_bounds__(256) void ka_attn(
    const float* __restrict__ dep, const float* __restrict__ zs,
    const float* __restrict__ s_i, const float* __restrict__ s_j,
    const float* __restrict__ wa, const float* __restrict__ ba,
    const int* __restrict__ nasp, const int* __restrict__ aspect_idx,
    const int* __restrict__ aj_cnt, const int* __restrict__ aj_idx,
    float* __restrict__ X2g) {
  int b = blockIdx.x;
  int na = nasp[b];
  if (na == 0) return;
  __shared__ float att[4][128];
  __shared__ int jl[4][128];
  __shared__ int aidx[4];
  __shared__ int ajc[4];
  __shared__ float wae[64];
  int tid = threadIdx.x;
  if (tid < 4) { aidx[tid] = aspect_idx[b * 4 + tid]; ajc[tid] = aj_cnt[b * 4 + tid]; }
  if (tid < 64) wae[tid] = wa[1536 + tid];
  for (int q = tid; q < 512; q += 256) jl[q >> 7][q & 127] = aj_idx[b * 512 + q];
  __syncthreads();
  int w = tid >> 6, l = tid & 63;
  if (w >= na) return;
  int a = aidx[w], cj = ajc[w];
  float sib = s_i[b * 128 + a] + ba[0];
  const float* depa = dep + ((size_t)(b * 128 + a)) * 128 * 64;
  float sc0 = -INFINITY, sc1 = -INFINITY;
  for (int t = l; t < cj; t += 64) {
    int j = jl[w][t];
    const float4* dp = (const float4*)(depa + (size_t)j * 64);
    float se = 0.f;
#pragma unroll
    for (int q = 0; q < 16; ++q) {
      float4 v = dp[q];
      se += v.x * wae[4 * q] + v.y * wae[4 * q + 1] + v.z * wae[4 * q + 2] + v.w * wae[4 * q + 3];
    }
    float sc = sib + s_j[b * 128 + j] + se;
    sc = (sc >= 0.f) ? sc : 0.01f * sc;
    if (t < 64) sc0 = sc; else sc1 = sc;
  }
  float mx = fmaxf(sc0, sc1);
#pragma unroll
  for (int d = 32; d; d >>= 1) mx = fmaxf(mx, __shfl_xor(mx, d, 64));
  float p0 = expf(sc0 - mx), p1 = expf(sc1 - mx);
  float sm = p0 + p1;
#pragma unroll
  for (int d = 32; d; d >>= 1) sm += __shfl_xor(sm, d, 64);
  float inv = 1.f / sm;
  if (l < cj) att[w][l] = p0 * inv;
  if (l + 64 < cj) att[w][l + 64] = p1 * inv;
  // y = attn @ zs (12 regs/lane), D = attn @ dep_row; write to X2g global
  float y[12];
#pragma unroll
  for (int q = 0; q < 12; ++q) y[q] = 0.f;
  float dacc = 0.f;
  for (int t = 0; t < cj; ++t) {
    float at = att[w][t];
    int j = jl[w][t];
    const float* zr = zs + (size_t)(b * 128 + j) * 768;
#pragma unroll
    for (int q = 0; q < 12; ++q) y[q] += at * zr[q * 64 + l];
    dacc += at * depa[(size_t)j * 64 + l];
  }
  float* xr = X2g + (size_t)(b * 4 + w) * 832;
#pragma unroll
  for (int q = 0; q < 12; ++q) xr[q * 64 + l] = y[q];
  xr[768 + l] = dacc;
}

// ---------------- G1: nbr partials = X2g @ Wf^T (K=832, 2 chunks of 416) ----------------
__global__ __launch_bounds__(256) void gemv1_wf(
    const float* __restrict__ X2g, const float* __restrict__ Wf,
    float* __restrict__ nbr_part) {
  int g = blockIdx.x, nc = blockIdx.y, kc = blockIdx.z;
  int tid = threadIdx.x;
  __shared__ float Xs[4][416];
#pragma unroll
  for (int r = 0; r < 4; ++r) {
    if (tid < 104)
      ((float4*)Xs[r])[tid] = *((const float4*)(X2g + (size_t)(g * 4 + r) * 832 + kc * 416) + tid);
  }
  __syncthreads();
  int h = nc * 256 + tid;
  float acc[4] = {};
  const float4* wp = (const float4*)(Wf + (size_t)h * 832 + kc * 416);
#pragma unroll 4
  for (int k4 = 0; k4 < 104; ++k4) {
    float4 wv = wp[k4];
#pragma unroll
    for (int r = 0; r < 4; ++r) {
      float4 xv = ((const float4*)Xs[r])[k4];
      acc[r] += xv.x * wv.x + xv.y * wv.y + xv.z * wv.z + xv.w * wv.w;
    }
  }
#pragma unroll
  for (int r = 0; r < 4; ++r)
    nbr_part[((size_t)kc * 128 + g * 4 + r) * 768 + h] = acc[r];
}

// ---------------- G2: temp partials = [nbr|zsa] @ Wh^T (K=1536, 4 chunks of 384) ----------------
__global__ __launch_bounds__(256) void gemv2_wh(
    const float* __restrict__ nbr_part, const float* __restrict__ zs,
    const int* __restrict__ row_map, const float* __restrict__ Wh,
    float* __restrict__ temp_part) {
  int g = blockIdx.x, nc = blockIdx.y, kc = blockIdx.z;
  int tid = threadIdx.x;
  __shared__ float Xs[4][384];
  if (kc < 2) {  // nbr half: sum the two K-partials
#pragma unroll
    for (int r = 0; r < 4; ++r) {
      if (tid < 96) {
        int row = g * 4 + r;
        float4 p0 = *((const float4*)(nbr_part + (size_t)row * 768 + kc * 384) + tid);
        float4 p1 = *((const float4*)(nbr_part + ((size_t)128 + row) * 768 + kc * 384) + tid);
        ((float4*)Xs[r])[tid] = make_float4(p0.x + p1.x, p0.y + p1.y, p0.z + p1.z, p0.w + p1.w);
      }
    }
  } else {  // zsa half: zs[aspect row]
#pragma unroll
    for (int r = 0; r < 4; ++r) {
      if (tid < 96) {
        int zrow = row_map[g * 4 + r];
        ((float4*)Xs[r])[tid] = *((const float4*)(zs + (size_t)zrow * 768 + (kc - 2) * 384) + tid);
      }
    }
  }
  __syncthreads();
  int h = nc * 256 + tid;
  float acc[4] = {};
  const float4* wp = (const float4*)(Wh + (size_t)h * 1536 + kc * 384);
#pragma unroll 4
  for (int k4 = 0; k4 < 96; ++k4) {
    float4 wv = wp[k4];
#pragma unroll
    for (int r = 0; r < 4; ++r) {
      float4 xv = ((const float4*)Xs[r])[k4];
      acc[r] += xv.x * wv.x + xv.y * wv.y + xv.z * wv.z + xv.w * wv.w;
    }
  }
#pragma unroll
  for (int r = 0; r < 4; ++r)
    temp_part[((size_t)kc * 128 + g * 4 + r) * 768 + h] = acc[r];
}

// ---------------- K4: out = upd[i-1] ? sum(temp_part)[i-1] : bert[i] ----------------
__global__ __launch_bounds__(256) void k4_out(
    const float* __restrict__ bert, const float* __restrict__ temp_part,
    const int* __restrict__ aspect_slot, float* __restrict__ out) {
  int idx = blockIdx.x * 256 + threadIdx.x;  // float4 index
  if (idx >= NB * NL * NH / 4) return;
  int row = idx / 192;  // 192 float4 per row
  int c4 = idx - row * 192;
  int b = row >> 7, i = row & 127;
  int slot = -1;
  if (i > 0) slot = aspect_slot[b * 128 + i - 1];
  float4 v;
  if (slot >= 0) {
    int trow = b * 4 + slot;
    float4 a0 = *((const float4*)(temp_part + (size_t)trow * 768) + c4);
    float4 a1 = *((const float4*)(temp_part + ((size_t)128 + trow) * 768) + c4);
    float4 a2 = *((const float4*)(temp_part + ((size_t)256 + trow) * 768) + c4);
    float4 a3 = *((const float4*)(temp_part + ((size_t)384 + trow) * 768) + c4);
    v = make_float4(a0.x + a1.x + a2.x + a3.x, a0.y + a1.y + a2.y + a3.y,
                    a0.z + a1.z + a2.z + a3.z, a0.w + a1.w + a2.w + a3.w);
  } else {
    v = *(const float4*)(bert + (size_t)row * 768 + c4 * 4);
  }
  *((float4*)out + idx) = v;
}

extern "C" void kernel_launch(void* const* d_in, const int* in_sizes, int n_in,
                              void* d_out, int out_size, void* d_ws, size_t ws_size,
                              hipStream_t stream) {
  const float* bert = (const float*)d_in[0];
  const float* dep  = (const float*)d_in[1];
  const int*   adj  = (const int*)d_in[2];
  const int*   asps = (const int*)d_in[3];
  const int*   aspe = (const int*)d_in[4];
  const float* Wz   = (const float*)d_in[5];
  const float* bz   = (const float*)d_in[6];
  const float* wa   = (const float*)d_in[7];
  const float* ba   = (const float*)d_in[8];
  const float* Wf   = (const float*)d_in[9];
  const float* Wh   = (const float*)d_in[10];
  float* out = (float*)d_out;
  char* ws = (char*)d_ws;

  int*   g_total     = (int*)(ws + OFF_TOTAL);
  int*   nr_list     = (int*)(ws + OFF_NRLIST);
  int*   aspect_slot = (int*)(ws + OFF_ASLOT);
  int*   aspect_idx  = (int*)(ws + OFF_AIDX);
  int*   nasp        = (int*)(ws + OFF_NASP);
  int*   aj_cnt      = (int*)(ws + OFF_AJCNT);
  int*   aj_idx      = (int*)(ws + OFF_AJIDX);
  float* s_i         = (float*)(ws + OFF_SI);
  float* s_j         = (float*)(ws + OFF_SJ);
  int*   row_map     = (int*)(ws + OFF_RMAP);
  float* X2g         = (float*)(ws + OFF_X2G);
  float* nbr_part    = (float*)(ws + OFF_NBRP);
  float* temp_part   = (float*)(ws + OFF_TEMPP);
  float* zs          = (float*)(ws + OFF_ZS);

  hipMemsetAsync(g_total, 0, 16, stream);
  k1_masks<<<NB, 128, 0, stream>>>(adj, asps, aspe, g_total, nr_list, aspect_slot,
                                   aspect_idx, nasp, aj_cnt, aj_idx, row_map);
  k2_zs<<<dim3(1024, 3), 256, 0, stream>>>(bert, Wz, bz, g_total, nr_list, zs);
  k2b_sij<<<16, 256, 0, stream>>>(zs, wa, g_total, nr_list, s_i, s_j);
  ka_attn<<<NB, 256, 0, stream>>>(dep, zs, s_i, s_j, wa, ba,
                                  nasp, aspect_idx, aj_cnt, aj_idx, X2g);
  gemv1_wf<<<dim3(32, 3, 2), 256, 0, stream>>>(X2g, Wf, nbr_part);
  gemv2_wh<<<dim3(32, 3, 4), 256, 0, stream>>>(nbr_part, zs, row_map, Wh, temp_part);
  k4_out<<<(NB * NL * NH / 4 + 255) / 256, 256, 0, stream>>>(bert, temp_part, aspect_slot, out);
}

// Round 6
// 198.656 us; speedup vs baseline: 1.5926x; 1.0285x over previous
//
#include <hip/hip_runtime.h>
#include <math.h>

// Shapes: B=32, L=128, H=768, E=64, H+E=832, 2H=1536
#define NB 32
#define NL 128
#define NH 768
#define NE 64

// ---------------- ws layout (bytes) ----------------
#define OFF_TOTAL   0         // int g_total (16 B reserved)
#define OFF_NRLIST  16        // int[4096*2] (b,i) pairs            -> 32784
#define OFF_ASLOT   32784     // int[32*128] aspect slot or -1      -> 49168
#define OFF_AIDX    49168     // int[32*4] aspect row index         -> 49680
#define OFF_NASP    49680     // int[32]                            -> 49808
#define OFF_AJCNT   49808     // int[32*4]                          -> 50320
#define OFF_AJIDX   50320     // int[32*4*128]                      -> 115856
#define OFF_SI      115856    // float[4096]                        -> 132240
#define OFF_SJ      132240    // float[4096]                        -> 148624
#define OFF_RMAP    148624    // int[128] zs-row index per (b,slot) -> 149136
#define OFF_X2G     149152    // float[128*832]  [y|D]              -> 575136
#define OFF_NBRP    575136    // float[2*128*768] nbr partials      -> 1361568
#define OFF_TEMPP   1361568   // float[4*128*768] temp partials     -> 2934432
#define OFF_ZS      2934432   // float[32*128*768]                  -> 15517344

// ---------------- K1: masks, aspect rows, needed-row compaction ----------------
__global__ __launch_bounds__(128) void k1_masks(
    const int* __restrict__ adj, const int* __restrict__ asp_s, const int* __restrict__ asp_e,
    int* __restrict__ g_total, int* __restrict__ nr_list, int* __restrict__ aspect_slot,
    int* __restrict__ aspect_idx, int* __restrict__ nasp, int* __restrict__ aj_cnt,
    int* __restrict__ aj_idx, int* __restrict__ row_map) {
  int b = blockIdx.x, tid = threadIdx.x;
  __shared__ int asp_flag[128];
  __shared__ int needed[128];
  __shared__ int s_aidx[4];
  __shared__ int s_nasp;
  const int* arow = adj + ((size_t)(b * 128 + tid)) * 128;
  int any = 0;
  for (int j = 0; j < 128; j += 4) {
    int4 v = *(const int4*)(arow + j);
    any |= v.x | v.y | v.z | v.w;
  }
  int s0 = asp_s[b], e0 = asp_e[b];
  int af = (tid >= s0 && tid <= e0 && any > 0) ? 1 : 0;
  asp_flag[tid] = af;
  aspect_slot[b * 128 + tid] = -1;
  __syncthreads();
  if (tid == 0) {
    int n = 0;
    for (int i = 0; i < 128; ++i)
      if (asp_flag[i] && n < 4) s_aidx[n++] = i;
    s_nasp = n;
    nasp[b] = n;
  }
  __syncthreads();
  int na = s_nasp;
  int nd = af;
  for (int s = 0; s < na; ++s) {
    int a = s_aidx[s];
    nd |= (adj[((size_t)(b * 128 + a)) * 128 + tid] > 0) ? 1 : 0;
  }
  needed[tid] = nd;
  if (tid < 4) row_map[b * 4 + tid] = b * 128;  // safe default for invalid slots
  if (tid < na) {
    int a = s_aidx[tid];
    aspect_idx[b * 4 + tid] = a;
    aspect_slot[b * 128 + a] = tid;
    row_map[b * 4 + tid] = b * 128 + a;
    int c = 0;
    const int* ar = adj + ((size_t)(b * 128 + a)) * 128;
    for (int j = 0; j < 128; ++j)
      if (ar[j] > 0) aj_idx[(b * 4 + tid) * 128 + (c++)] = j;
    aj_cnt[b * 4 + tid] = c;
  }
  __syncthreads();
  if (tid == 0) {
    int c = 0;
    for (int i = 0; i < 128; ++i) c += needed[i];
    int base = atomicAdd(g_total, c);
    int k = 0;
    for (int i = 0; i < 128; ++i)
      if (needed[i]) { nr_list[2 * (base + k)] = b; nr_list[2 * (base + k) + 1] = i; ++k; }
  }
}

// ---------------- K2 (v4): zs = roll(bert@Wz^T + bz) for needed rows ----------------
// grid (1024, 6), block 128: 4 rows/block, h-chunk of 128 per block.y.
// X rows in LDS (uniform b128 broadcast); thread streams 1 Wz row in TWO
// independent K-half chains (8 outstanding loads w/ unroll 4, half dep depth).
__global__ __launch_bounds__(128) void k2_zs(
    const float* __restrict__ bert, const float* __restrict__ Wz, const float* __restrict__ bz,
    const int* __restrict__ g_total, const int* __restrict__ nr_list, float* __restrict__ zs) {
  int total = *g_total;
  int row0 = blockIdx.x * 4;
  if (row0 >= total) return;
  __shared__ float Xs[4][768];
  int tid = threadIdx.x;
  for (int r = 0; r < 4; ++r) {
    int s = row0 + r;
    if (s < total) {
      int bb = nr_list[2 * s], ii = nr_list[2 * s + 1];
      const float4* src = (const float4*)(bert + ((size_t)(bb * 128) + ((ii + 1) & 127)) * 768);
      for (int q = tid; q < 192; q += 128) ((float4*)Xs[r])[q] = src[q];
    }
  }
  __syncthreads();
  int h = blockIdx.y * 128 + tid;
  const float4* wp = (const float4*)(Wz + (size_t)h * 768);
  float accA[4] = {};
  float accB[4] = {};
#pragma unroll 4
  for (int k4 = 0; k4 < 96; ++k4) {
    float4 w0 = wp[k4];
    float4 w1 = wp[k4 + 96];
#pragma unroll
    for (int r = 0; r < 4; ++r) {
      float4 x0 = ((const float4*)Xs[r])[k4];
      float4 x1 = ((const float4*)Xs[r])[k4 + 96];
      accA[r] += x0.x * w0.x + x0.y * w0.y + x0.z * w0.z + x0.w * w0.w;
      accB[r] += x1.x * w1.x + x1.y * w1.y + x1.z * w1.z + x1.w * w1.w;
    }
  }
  float bzv = bz[h];
#pragma unroll
  for (int r = 0; r < 4; ++r) {
    int s = row0 + r;
    if (s < total) {
      int bb = nr_list[2 * s], ii = nr_list[2 * s + 1];
      zs[(size_t)(bb * 128 + ii) * 768 + h] = accA[r] + accB[r] + bzv;
    }
  }
}

// ---------------- K2b: s_i, s_j dots for needed rows ----------------
__global__ __launch_bounds__(256) void k2b_sij(
    const float* __restrict__ zs, const float* __restrict__ wa,
    const int* __restrict__ g_total, const int* __restrict__ nr_list,
    float* __restrict__ s_i, float* __restrict__ s_j) {
  int gw = (blockIdx.x * 256 + threadIdx.x) >> 6;
  int l = threadIdx.x & 63;
  int total = *g_total;
  for (int s = gw; s < total; s += 256) {
    int b = nr_list[2 * s], i = nr_list[2 * s + 1];
    const float* zr = zs + (size_t)(b * 128 + i) * 768;
    float si = 0.f, sj = 0.f;
#pragma unroll
    for (int q = 0; q < 12; ++q) {
      float v = zr[q * 64 + l];
      si += v * wa[q * 64 + l];
      sj += v * wa[768 + q * 64 + l];
    }
#pragma unroll
    for (int d = 32; d; d >>= 1) {
      si += __shfl_xor(si, d, 64);
      sj += __shfl_xor(sj, d, 64);
    }
    if (l == 0) { s_i[b * 128 + i] = si; s_j[b * 128 + i] = sj; }
  }
}

// ---------------- KA: per-batch attention: scores, softmax, y, D -> X2g[row][832] ----------------
__global__ __launch_bounds__(256) void ka_attn(
    const float* __restrict__ dep, const float* __restrict__ zs,
    const float* __restrict__ s_i, const float* __restrict__ s_j,
    const float* __restrict__ wa, const float* __restrict__ ba,
    const int* __restrict__ nasp, const int* __restrict__ aspect_idx,
    const int* __restrict__ aj_cnt, const int* __restrict__ aj_idx,
    float* __restrict__ X2g) {
  int b = blockIdx.x;
  int na = nasp[b];
  if (na == 0) return;
  __shared__ float att[4][128];
  __shared__ int jl[4][128];
  __shared__ int aidx[4];
  __shared__ int ajc[4];
  __shared__ float wae[64];
  int tid = threadIdx.x;
  if (tid < 4) { aidx[tid] = aspect_idx[b * 4 + tid]; ajc[tid] = aj_cnt[b * 4 + tid]; }
  if (tid < 64) wae[tid] = wa[1536 + tid];
  for (int q = tid; q < 512; q += 256) jl[q >> 7][q & 127] = aj_idx[b * 512 + q];
  __syncthreads();
  int w = tid >> 6, l = tid & 63;
  if (w >= na) return;
  int a = aidx[w], cj = ajc[w];
  float sib = s_i[b * 128 + a] + ba[0];
  const float* depa = dep + ((size_t)(b * 128 + a)) * 128 * 64;
  float sc0 = -INFINITY, sc1 = -INFINITY;
  for (int t = l; t < cj; t += 64) {
    int j = jl[w][t];
    const float4* dp = (const float4*)(depa + (size_t)j * 64);
    float se = 0.f;
#pragma unroll
    for (int q = 0; q < 16; ++q) {
      float4 v = dp[q];
      se += v.x * wae[4 * q] + v.y * wae[4 * q + 1] + v.z * wae[4 * q + 2] + v.w * wae[4 * q + 3];
    }
    float sc = sib + s_j[b * 128 + j] + se;
    sc = (sc >= 0.f) ? sc : 0.01f * sc;
    if (t < 64) sc0 = sc; else sc1 = sc;
  }
  float mx = fmaxf(sc0, sc1);
#pragma unroll
  for (int d = 32; d; d >>= 1) mx = fmaxf(mx, __shfl_xor(mx, d, 64));
  float p0 = expf(sc0 - mx), p1 = expf(sc1 - mx);
  float sm = p0 + p1;
#pragma unroll
  for (int d = 32; d; d >>= 1) sm += __shfl_xor(sm, d, 64);
  float inv = 1.f / sm;
  if (l < cj) att[w][l] = p0 * inv;
  if (l + 64 < cj) att[w][l + 64] = p1 * inv;
  // y = attn @ zs (12 regs/lane), D = attn @ dep_row; write to X2g global
  float y[12];
#pragma unroll
  for (int q = 0; q < 12; ++q) y[q] = 0.f;
  float dacc = 0.f;
  for (int t = 0; t < cj; ++t) {
    float at = att[w][t];
    int j = jl[w][t];
    const float* zr = zs + (size_t)(b * 128 + j) * 768;
#pragma unroll
    for (int q = 0; q < 12; ++q) y[q] += at * zr[q * 64 + l];
    dacc += at * depa[(size_t)j * 64 + l];
  }
  float* xr = X2g + (size_t)(b * 4 + w) * 832;
#pragma unroll
  for (int q = 0; q < 12; ++q) xr[q * 64 + l] = y[q];
  xr[768 + l] = dacc;
}

// ---------------- G1: nbr partials = X2g @ Wf^T (K=832, 2 chunks of 416) ----------------
__global__ __launch_bounds__(256) void gemv1_wf(
    const float* __restrict__ X2g, const float* __restrict__ Wf,
    float* __restrict__ nbr_part) {
  int g = blockIdx.x, nc = blockIdx.y, kc = blockIdx.z;
  int tid = threadIdx.x;
  __shared__ float Xs[4][416];
#pragma unroll
  for (int r = 0; r < 4; ++r) {
    if (tid < 104)
      ((float4*)Xs[r])[tid] = *((const float4*)(X2g + (size_t)(g * 4 + r) * 832 + kc * 416) + tid);
  }
  __syncthreads();
  int h = nc * 256 + tid;
  float acc[4] = {};
  const float4* wp = (const float4*)(Wf + (size_t)h * 832 + kc * 416);
#pragma unroll 4
  for (int k4 = 0; k4 < 104; ++k4) {
    float4 wv = wp[k4];
#pragma unroll
    for (int r = 0; r < 4; ++r) {
      float4 xv = ((const float4*)Xs[r])[k4];
      acc[r] += xv.x * wv.x + xv.y * wv.y + xv.z * wv.z + xv.w * wv.w;
    }
  }
#pragma unroll
  for (int r = 0; r < 4; ++r)
    nbr_part[((size_t)kc * 128 + g * 4 + r) * 768 + h] = acc[r];
}

// ---------------- G2: temp partials = [nbr|zsa] @ Wh^T (K=1536, 4 chunks of 384) ----------------
__global__ __launch_bounds__(256) void gemv2_wh(
    const float* __restrict__ nbr_part, const float* __restrict__ zs,
    const int* __restrict__ row_map, const float* __restrict__ Wh,
    float* __restrict__ temp_part) {
  int g = blockIdx.x, nc = blockIdx.y, kc = blockIdx.z;
  int tid = threadIdx.x;
  __shared__ float Xs[4][384];
  if (kc < 2) {  // nbr half: sum the two K-partials
#pragma unroll
    for (int r = 0; r < 4; ++r) {
      if (tid < 96) {
        int row = g * 4 + r;
        float4 p0 = *((const float4*)(nbr_part + (size_t)row * 768 + kc * 384) + tid);
        float4 p1 = *((const float4*)(nbr_part + ((size_t)128 + row) * 768 + kc * 384) + tid);
        ((float4*)Xs[r])[tid] = make_float4(p0.x + p1.x, p0.y + p1.y, p0.z + p1.z, p0.w + p1.w);
      }
    }
  } else {  // zsa half: zs[aspect row]
#pragma unroll
    for (int r = 0; r < 4; ++r) {
      if (tid < 96) {
        int zrow = row_map[g * 4 + r];
        ((float4*)Xs[r])[tid] = *((const float4*)(zs + (size_t)zrow * 768 + (kc - 2) * 384) + tid);
      }
    }
  }
  __syncthreads();
  int h = nc * 256 + tid;
  float acc[4] = {};
  const float4* wp = (const float4*)(Wh + (size_t)h * 1536 + kc * 384);
#pragma unroll 4
  for (int k4 = 0; k4 < 96; ++k4) {
    float4 wv = wp[k4];
#pragma unroll
    for (int r = 0; r < 4; ++r) {
      float4 xv = ((const float4*)Xs[r])[k4];
      acc[r] += xv.x * wv.x + xv.y * wv.y + xv.z * wv.z + xv.w * wv.w;
    }
  }
#pragma unroll
  for (int r = 0; r < 4; ++r)
    temp_part[((size_t)kc * 128 + g * 4 + r) * 768 + h] = acc[r];
}

// ---------------- K4: out = upd[i-1] ? sum(temp_part)[i-1] : bert[i] ----------------
__global__ __launch_bounds__(256) void k4_out(
    const float* __restrict__ bert, const float* __restrict__ temp_part,
    const int* __restrict__ aspect_slot, float* __restrict__ out) {
  int idx = blockIdx.x * 256 + threadIdx.x;  // float4 index
  if (idx >= NB * NL * NH / 4) return;
  int row = idx / 192;  // 192 float4 per row
  int c4 = idx - row * 192;
  int b = row >> 7, i = row & 127;
  int slot = -1;
  if (i > 0) slot = aspect_slot[b * 128 + i - 1];
  float4 v;
  if (slot >= 0) {
    int trow = b * 4 + slot;
    float4 a0 = *((const float4*)(temp_part + (size_t)trow * 768) + c4);
    float4 a1 = *((const float4*)(temp_part + ((size_t)128 + trow) * 768) + c4);
    float4 a2 = *((const float4*)(temp_part + ((size_t)256 + trow) * 768) + c4);
    float4 a3 = *((const float4*)(temp_part + ((size_t)384 + trow) * 768) + c4);
    v = make_float4(a0.x + a1.x + a2.x + a3.x, a0.y + a1.y + a2.y + a3.y,
                    a0.z + a1.z + a2.z + a3.z, a0.w + a1.w + a2.w + a3.w);
  } else {
    v = *(const float4*)(bert + (size_t)row * 768 + c4 * 4);
  }
  *((float4*)out + idx) = v;
}

extern "C" void kernel_launch(void* const* d_in, const int* in_sizes, int n_in,
                              void* d_out, int out_size, void* d_ws, size_t ws_size,
                              hipStream_t stream) {
  const float* bert = (const float*)d_in[0];
  const float* dep  = (const float*)d_in[1];
  const int*   adj  = (const int*)d_in[2];
  const int*   asps = (const int*)d_in[3];
  const int*   aspe = (const int*)d_in[4];
  const float* Wz   = (const float*)d_in[5];
  const float* bz   = (const float*)d_in[6];
  const float* wa   = (const float*)d_in[7];
  const float* ba   = (const float*)d_in[8];
  const float* Wf   = (const float*)d_in[9];
  const float* Wh   = (const float*)d_in[10];
  float* out = (float*)d_out;
  char* ws = (char*)d_ws;

  int*   g_total     = (int*)(ws + OFF_TOTAL);
  int*   nr_list     = (int*)(ws + OFF_NRLIST);
  int*   aspect_slot = (int*)(ws + OFF_ASLOT);
  int*   aspect_idx  = (int*)(ws + OFF_AIDX);
  int*   nasp        = (int*)(ws + OFF_NASP);
  int*   aj_cnt      = (int*)(ws + OFF_AJCNT);
  int*   aj_idx      = (int*)(ws + OFF_AJIDX);
  float* s_i         = (float*)(ws + OFF_SI);
  float* s_j         = (float*)(ws + OFF_SJ);
  int*   row_map     = (int*)(ws + OFF_RMAP);
  float* X2g         = (float*)(ws + OFF_X2G);
  float* nbr_part    = (float*)(ws + OFF_NBRP);
  float* temp_part   = (float*)(ws + OFF_TEMPP);
  float* zs          = (float*)(ws + OFF_ZS);

  hipMemsetAsync(g_total, 0, 16, stream);
  k1_masks<<<NB, 128, 0, stream>>>(adj, asps, aspe, g_total, nr_list, aspect_slot,
                                   aspect_idx, nasp, aj_cnt, aj_idx, row_map);
  k2_zs<<<dim3(1024, 6), 128, 0, stream>>>(bert, Wz, bz, g_total, nr_list, zs);
  k2b_sij<<<64, 256, 0, stream>>>(zs, wa, g_total, nr_list, s_i, s_j);
  ka_attn<<<NB, 256, 0, stream>>>(dep, zs, s_i, s_j, wa, ba,
                                  nasp, aspect_idx, aj_cnt, aj_idx, X2g);
  gemv1_wf<<<dim3(32, 3, 2), 256, 0, stream>>>(X2g, Wf, nbr_part);
  gemv2_wh<<<dim3(32, 3, 4), 256, 0, stream>>>(nbr_part, zs, row_map, Wh, temp_part);
  k4_out<<<(NB * NL * NH / 4 + 255) / 256, 256, 0, stream>>>(bert, temp_part, aspect_slot, out);
}